// Round 1
// baseline (684.219 us; speedup 1.0000x reference)
//
#include <hip/hip_runtime.h>

#define GX 128
#define NUM_EMB (GX * GX * GX)
// EMB_DIM = 32 floats = 8 float4 per row

__global__ __launch_bounds__(256) void grid_emb_kernel(
    const float* __restrict__ x,
    const float4* __restrict__ emb4,
    float4* __restrict__ out4,
    int n_pts)
{
    int tid = blockIdx.x * 256 + threadIdx.x;
    int p = tid >> 3;   // point index
    int g = tid & 7;    // float4 group within the 32-dim row
    if (p >= n_pts) return;

    float xr0 = x[3 * p + 0] * (float)GX;
    float xr1 = x[3 * p + 1] * (float)GX;
    float xr2 = x[3 * p + 2] * (float)GX;
    float f0 = floorf(xr0), f1 = floorf(xr1), f2 = floorf(xr2);
    float w0 = xr0 - f0, w1 = xr1 - f1, w2 = xr2 - f2;

    int c000 = (int)f0 + (int)f1 * GX + (int)f2 * (GX * GX);
    if (c000 >= NUM_EMB) c000 = NUM_EMB - 1;

    // Reference corner order / clamp semantics (clamp-to-c000, NOT per-axis):
    int c[8];
    c[0] = c000;                       // v000
    c[1] = c000 + 1;                   // v001  (weight m0*m1*w2)
    c[2] = c000 + GX;                  // v010  (m0*w1*m2)
    c[3] = c000 + GX * GX;             // v100  (w0*m1*m2)
    c[4] = c000 + GX + 1;              // v011  (m0*w1*w2)
    c[5] = c000 + GX * GX + 1;         // v101  (w0*m1*w2)
    c[6] = c000 + GX * GX + GX;        // v110  (w0*w1*m2)
    c[7] = c000 + GX * GX + GX + 1;    // v111  (w0*w1*w2)
#pragma unroll
    for (int k = 1; k < 8; ++k) c[k] = (c[k] >= NUM_EMB) ? c000 : c[k];

    float m0 = 1.f - w0, m1 = 1.f - w1, m2 = 1.f - w2;
    float wt[8];
    wt[0] = m0 * m1 * m2;
    wt[1] = m0 * m1 * w2;
    wt[2] = m0 * w1 * m2;
    wt[3] = w0 * m1 * m2;
    wt[4] = m0 * w1 * w2;
    wt[5] = w0 * m1 * w2;
    wt[6] = w0 * w1 * m2;
    wt[7] = w0 * w1 * w2;

    // Issue all 8 gathers up front — independent loads, max memory-level parallelism.
    float4 v[8];
#pragma unroll
    for (int k = 0; k < 8; ++k) v[k] = emb4[c[k] * 8 + g];

    float4 acc;
    acc.x = 0.f; acc.y = 0.f; acc.z = 0.f; acc.w = 0.f;
#pragma unroll
    for (int k = 0; k < 8; ++k) {
        acc.x = fmaf(wt[k], v[k].x, acc.x);
        acc.y = fmaf(wt[k], v[k].y, acc.y);
        acc.z = fmaf(wt[k], v[k].z, acc.z);
        acc.w = fmaf(wt[k], v[k].w, acc.w);
    }

    out4[p * 8 + g] = acc;
}

extern "C" void kernel_launch(void* const* d_in, const int* in_sizes, int n_in,
                              void* d_out, int out_size, void* d_ws, size_t ws_size,
                              hipStream_t stream) {
    const float* x = (const float*)d_in[0];          // (N_PTS, 3) f32
    const float4* emb4 = (const float4*)d_in[1];     // (NUM_EMB, 32) f32 as float4
    float4* out4 = (float4*)d_out;                   // (N_PTS, 32) f32 as float4

    int n_pts = in_sizes[0] / 3;
    int total_threads = n_pts * 8;
    int blocks = (total_threads + 255) / 256;
    grid_emb_kernel<<<blocks, 256, 0, stream>>>(x, emb4, out4, n_pts);
}